// Round 4
// baseline (274.592 us; speedup 1.0000x reference)
//
#include <hip/hip_runtime.h>
#include <hip/hip_bf16.h>

#define TOPK 30
#define NAT 14
#define EDGE_IN 3152   // 16 PE + 14*14*16 RBF
#define KPAD 3168      // padded to 99 chunks of 32
#define NCHUNK 99
#define EPB 32         // edges per k_edge block

typedef __attribute__((ext_vector_type(8))) short bf16x8;
typedef __attribute__((ext_vector_type(4))) float f32x4;

__device__ __forceinline__ unsigned short f2bf(float f) {
    union { float f; unsigned u; } v; v.f = f;
    unsigned r = v.u + 0x7FFF + ((v.u >> 16) & 1);   // RNE
    return (unsigned short)(r >> 16);
}

// ---------------- Xa = [N, Ca, C, O, Cb, sc9] ----------------
__global__ void k_prep(const float* __restrict__ X, float* __restrict__ Xa, int N) {
    int i = blockIdx.x * blockDim.x + threadIdx.x;
    if (i >= N) return;
    const float* xi = X + (size_t)i * NAT * 3;
    float* xo = Xa + (size_t)i * NAT * 3;
    float Nx = xi[0], Ny = xi[1], Nz = xi[2];
    float Ax = xi[3], Ay = xi[4], Az = xi[5];
    float Cx = xi[6], Cy = xi[7], Cz = xi[8];
    float bx = Ax - Nx, by = Ay - Ny, bz = Az - Nz;   // b = Ca - N
    float cx = Cx - Ax, cy = Cy - Ay, cz = Cz - Az;   // c = C - Ca
    float ax = by * cz - bz * cy;                     // a = cross(b,c)
    float ay = bz * cx - bx * cz;
    float az = bx * cy - by * cx;
    float Cbx = -0.58273431f * ax + 0.56802827f * bx - 0.54067466f * cx + Ax;
    float Cby = -0.58273431f * ay + 0.56802827f * by - 0.54067466f * cy + Ay;
    float Cbz = -0.58273431f * az + 0.56802827f * bz - 0.54067466f * cz + Az;
#pragma unroll
    for (int a = 0; a < 4; a++) { xo[a*3] = xi[a*3]; xo[a*3+1] = xi[a*3+1]; xo[a*3+2] = xi[a*3+2]; }
    xo[12] = Cbx; xo[13] = Cby; xo[14] = Cbz;
#pragma unroll
    for (int a = 5; a < 14; a++) { xo[a*3] = xi[a*3]; xo[a*3+1] = xi[a*3+1]; xo[a*3+2] = xi[a*3+2]; }
}

// ---------------- Wt[c][k] = bf16(edge_w[k][c]), zero-padded to KPAD ----------------
__global__ void k_wt(const float* __restrict__ W, unsigned short* __restrict__ Wt) {
    __shared__ unsigned short tile[32][33];
    int kb = blockIdx.x * 32, cb = blockIdx.y * 32;
    int tx = threadIdx.x, ty = threadIdx.y;   // (32,8)
#pragma unroll
    for (int r = 0; r < 32; r += 8) {
        int k = kb + ty + r;
        float v = (k < EDGE_IN) ? W[(size_t)k * 128 + cb + tx] : 0.f;
        tile[ty + r][tx] = f2bf(v);
    }
    __syncthreads();
#pragma unroll
    for (int r = 0; r < 32; r += 8)
        Wt[(size_t)(cb + ty + r) * KPAD + kb + tx] = tile[tx][ty + r];
}

// ---------------- exact stable KNN in FLOAT64 (one block per residue) ----------------
__global__ __launch_bounds__(256) void k_knn(const float* __restrict__ X, const float* __restrict__ mask,
                                             int* __restrict__ Eidx, float* __restrict__ outI, int N) {
    __shared__ double sD[1024];
    __shared__ double sMax[4];
    __shared__ double sBd[4];
    __shared__ int    sBi[4];
    int i = blockIdx.x, t = threadIdx.x;
    double mi = (double)mask[i];
    double xx = (double)X[((size_t)i * NAT + 1) * 3 + 0];
    double xy = (double)X[((size_t)i * NAT + 1) * 3 + 1];
    double xz = (double)X[((size_t)i * NAT + 1) * 3 + 2];
    double lmax = -1.0;
    for (int j = t; j < N; j += 256) {
        double dx = xx - (double)X[((size_t)j * NAT + 1) * 3 + 0];
        double dy = xy - (double)X[((size_t)j * NAT + 1) * 3 + 1];
        double dz = xz - (double)X[((size_t)j * NAT + 1) * 3 + 2];
        double s = ((dx * dx + dy * dy) + dz * dz) + 1e-6;
        double d = (mi * (double)mask[j]) * sqrt(s);
        sD[j] = d;
        lmax = fmax(lmax, d);
    }
#pragma unroll
    for (int m = 32; m; m >>= 1) lmax = fmax(lmax, __shfl_xor(lmax, m));
    if ((t & 63) == 0) sMax[t >> 6] = lmax;
    __syncthreads();
    double Dmax = fmax(fmax(sMax[0], sMax[1]), fmax(sMax[2], sMax[3]));
    for (int j = t; j < N; j += 256) {
        double m2 = mi * (double)mask[j];
        sD[j] = sD[j] + 2.0 * (1.0 - m2) * Dmax;
    }
    __syncthreads();
    for (int s = 0; s < TOPK; s++) {
        double bd = 1e300;
        int bi = 0x7FFFFFFF;
        for (int j = t; j < N; j += 256) {
            double d = sD[j];
            if (d < bd || (d == bd && j < bi)) { bd = d; bi = j; }
        }
#pragma unroll
        for (int m = 32; m; m >>= 1) {
            double od = __shfl_xor(bd, m);
            int oi = __shfl_xor(bi, m);
            if (od < bd || (od == bd && oi < bi)) { bd = od; bi = oi; }
        }
        if ((t & 63) == 0) { sBd[t >> 6] = bd; sBi[t >> 6] = bi; }
        __syncthreads();
        if (t == 0) {
            double d0 = sBd[0]; int i0 = sBi[0];
#pragma unroll
            for (int w = 1; w < 4; w++) {
                if (sBd[w] < d0 || (sBd[w] == d0 && sBi[w] < i0)) { d0 = sBd[w]; i0 = sBi[w]; }
            }
            Eidx[(size_t)i * TOPK + s] = i0;
            outI[(size_t)i * TOPK + s] = (float)i0;
            sD[i0] = 1e300;
        }
        __syncthreads();
    }
}

// ---------------- node: onehot-gather + matvec + LN (one wave per residue) ----------------
__global__ __launch_bounds__(64) void k_node(const int* __restrict__ S, const float* __restrict__ BB,
                                             const float* __restrict__ W, const float* __restrict__ nb,
                                             const float* __restrict__ g, const float* __restrict__ be,
                                             float* __restrict__ outV, int N) {
    int i = blockIdx.x, t = threadIdx.x;
    int s = S[i];
    float b0 = BB[i*6], b1 = BB[i*6+1], b2 = BB[i*6+2], b3 = BB[i*6+3], b4 = BB[i*6+4], b5 = BB[i*6+5];
    int t2 = t + 64;
    float x0 = W[(size_t)s*128 + t] + nb[t]
             + b0*W[21*128+t] + b1*W[22*128+t] + b2*W[23*128+t]
             + b3*W[24*128+t] + b4*W[25*128+t] + b5*W[26*128+t];
    float x1 = W[(size_t)s*128 + t2] + nb[t2]
             + b0*W[21*128+t2] + b1*W[22*128+t2] + b2*W[23*128+t2]
             + b3*W[24*128+t2] + b4*W[25*128+t2] + b5*W[26*128+t2];
    float sum = x0 + x1;
#pragma unroll
    for (int m = 32; m; m >>= 1) sum += __shfl_xor(sum, m);
    float mean = sum * (1.f / 128.f);
    float d0 = x0 - mean, d1 = x1 - mean;
    float vs = d0*d0 + d1*d1;
#pragma unroll
    for (int m = 32; m; m >>= 1) vs += __shfl_xor(vs, m);
    float inv = 1.f / sqrtf(vs * (1.f / 128.f) + 1e-5f);
    outV[(size_t)i*128 + t]  = d0 * inv * g[t]  + be[t];
    outV[(size_t)i*128 + t2] = d1 * inv * g[t2] + be[t2];
}

// ---------------- fused edge features + bf16 MFMA GEMM + LN ----------------
// 32 edges/block, 8 waves: wave = (egrp in {0,1}) x (K-parity in {0..3}).
// Each wave: 16 edges x 128 cols, chunks kc = parity, parity+4, ... (4-way K-split).
// Partial accumulators reduced via LDS; parity-0 waves do LN epilogue.
__global__ __launch_bounds__(512, 6) void k_edge(const float* __restrict__ Xa, const int* __restrict__ Eidx,
                                                 const unsigned short* __restrict__ Wt,
                                                 const float* __restrict__ ebias, const float* __restrict__ egain,
                                                 const float* __restrict__ ebeta,
                                                 float* __restrict__ outE, int N) {
    __shared__ float sD[EPB * 197];   // 25216 B, stride 197: conflict-light; reused as reduction buffer
    __shared__ float sDpe[EPB];
    const int NE = N * TOPK;
    int t = threadIdx.x;
    int geBase = blockIdx.x * EPB;
    {
        int le = t >> 4, q = t & 15;      // 16 threads per edge
        int ge = geBase + le; if (ge >= NE) ge = NE - 1;
        int i = ge / TOPK;
        int j = Eidx[ge];
        if (q == 0) sDpe[le] = (float)j - (float)i;
        const float* Xi = Xa + (size_t)i * NAT * 3;
        const float* Xj = Xa + (size_t)j * NAT * 3;
        for (int p = q; p < 196; p += 16) {
            int a = p / 14, b = p - 14 * a;
            float dx = Xi[a*3+0] - Xj[b*3+0];
            float dy = Xi[a*3+1] - Xj[b*3+1];
            float dz = Xi[a*3+2] - Xj[b*3+2];
            sD[le * 197 + p] = sqrtf(dx*dx + dy*dy + dz*dz + 1e-6f);
        }
    }
    __syncthreads();

    int ln = t & 63, wid = t >> 6;
    int egrp = wid & 1, parity = wid >> 1;
    int lrow = ln & 15, koff = ln >> 4;
    int leA = egrp * 16 + lrow;          // this lane's A-row (edge)
    float dpe = sDpe[leA];
    const float* sDrow = sD + leA * 197;

    f32x4 acc[8];
#pragma unroll
    for (int f = 0; f < 8; f++) acc[f] = (f32x4){0.f, 0.f, 0.f, 0.f};

    const unsigned short* wcol[8];
#pragma unroll
    for (int f = 0; f < 8; f++) wcol[f] = Wt + (size_t)(f * 16 + lrow) * KPAD + koff * 8;

    for (int kc = parity; kc < NCHUNK; kc += 4) {
        int kb = kc * 32 + koff * 8;
        bf16x8 afrag;
        if (kb < 16) {
            // positional encoding: kb==0 -> cos(d*freq[j]), kb==8 -> sin(d*freq[j])
#pragma unroll
            for (int jj = 0; jj < 8; jj++) {
                float fr = __expf(-1.1512925f * (float)jj);   // 10000^(-2m/16)
                float ang = dpe * fr;
                float v = (kb == 0) ? cosf(ang) : sinf(ang);
                afrag[jj] = (short)f2bf(v);
            }
        } else if (kb >= EDGE_IN) {
#pragma unroll
            for (int jj = 0; jj < 8; jj++) afrag[jj] = 0;
        } else {
            int pk = kb - 16;                 // 8 consecutive k never cross a pair
            float D = sDrow[pk >> 4];
            float base = (float)(pk & 15);
#pragma unroll
            for (int jj = 0; jj < 8; jj++) {
                float mu = (base + (float)jj) * 1.3333334f;   // linspace(0,20,16)
                float tt = (D - mu) * 0.8f;                   // /1.25
                afrag[jj] = (short)f2bf(__expf(-tt * tt));
            }
        }
#pragma unroll
        for (int f = 0; f < 8; f++) {
            bf16x8 bfrag = *reinterpret_cast<const bf16x8*>(wcol[f] + kc * 32);
            acc[f] = __builtin_amdgcn_mfma_f32_16x16x32_bf16(afrag, bfrag, acc[f], 0, 0, 0);
        }
    }

    // ---- cross-wave K reduction: parities 1..3 fold into parity 0 via LDS ----
    __syncthreads();                       // main loop done; sD reusable
    f32x4* sAcc = reinterpret_cast<f32x4*>(sD);   // [(egrp*8+f)*64 + ln], 16 KB
    for (int src = 1; src < 4; src++) {
        if (parity == src) {
#pragma unroll
            for (int f = 0; f < 8; f++) sAcc[(egrp * 8 + f) * 64 + ln] = acc[f];
        }
        __syncthreads();
        if (parity == 0) {
#pragma unroll
            for (int f = 0; f < 8; f++) {
                f32x4 o = sAcc[(egrp * 8 + f) * 64 + ln];
                acc[f][0] += o[0]; acc[f][1] += o[1]; acc[f][2] += o[2]; acc[f][3] += o[3];
            }
        }
        __syncthreads();
    }
    if (parity != 0) return;               // no further barriers below

    // epilogue: +bias, LN over 128 cols (reduce across 16-lane group), f32 store
    float gg[8], bb2[8], eb[8];
#pragma unroll
    for (int f = 0; f < 8; f++) { int c = f * 16 + lrow; gg[f] = egain[c]; bb2[f] = ebeta[c]; eb[f] = ebias[c]; }
#pragma unroll
    for (int r = 0; r < 4; r++) {
        float x[8], sum = 0.f;
#pragma unroll
        for (int f = 0; f < 8; f++) { x[f] = acc[f][r] + eb[f]; sum += x[f]; }
#pragma unroll
        for (int m = 1; m < 16; m <<= 1) sum += __shfl_xor(sum, m);
        float mean = sum * (1.f / 128.f);
        float vs = 0.f;
#pragma unroll
        for (int f = 0; f < 8; f++) { float d2 = x[f] - mean; vs += d2 * d2; }
#pragma unroll
        for (int m = 1; m < 16; m <<= 1) vs += __shfl_xor(vs, m);
        float inv = 1.f / sqrtf(vs * (1.f / 128.f) + 1e-5f);
        int row = geBase + egrp * 16 + koff * 4 + r;
        if (row < NE) {
            float* po = outE + (size_t)row * 128 + lrow;
#pragma unroll
            for (int f = 0; f < 8; f++) po[f * 16] = (x[f] - mean) * inv * gg[f] + bb2[f];
        }
    }
}

extern "C" void kernel_launch(void* const* d_in, const int* in_sizes, int n_in,
                              void* d_out, int out_size, void* d_ws, size_t ws_size,
                              hipStream_t stream) {
    const float* X       = (const float*)d_in[0];
    const int*   S       = (const int*)d_in[1];
    const float* BB      = (const float*)d_in[2];
    const float* mask    = (const float*)d_in[3];
    const float* node_w  = (const float*)d_in[4];
    const float* node_b  = (const float*)d_in[5];
    const float* node_g  = (const float*)d_in[6];
    const float* node_lb = (const float*)d_in[7];
    const float* edge_w  = (const float*)d_in[8];
    const float* edge_b  = (const float*)d_in[9];
    const float* edge_g  = (const float*)d_in[10];
    const float* edge_lb = (const float*)d_in[11];
    int N  = in_sizes[1];       // 1024
    int NE = N * TOPK;

    float* out  = (float*)d_out;
    float* outV = out;                                  // N*128 f32
    float* outE = out + (size_t)N * 128;                // NE*128 f32
    float* outI = outE + (size_t)NE * 128;              // NE f32

    char* ws = (char*)d_ws;
    int* Eidx = (int*)ws;
    size_t off = ((size_t)NE * 4 + 255) & ~(size_t)255;
    float* Xa = (float*)(ws + off);
    off += (((size_t)N * NAT * 3 * 4) + 255) & ~(size_t)255;
    unsigned short* Wt = (unsigned short*)(ws + off);   // 128*KPAD bf16

    k_prep<<<dim3((N + 255) / 256), dim3(256), 0, stream>>>(X, Xa, N);
    k_wt<<<dim3(KPAD / 32, 128 / 32), dim3(32, 8), 0, stream>>>(edge_w, Wt);
    k_knn<<<dim3(N), dim3(256), 0, stream>>>(X, mask, Eidx, outI, N);
    k_node<<<dim3(N), dim3(64), 0, stream>>>(S, BB, node_w, node_b, node_g, node_lb, outV, N);
    k_edge<<<dim3((NE + EPB - 1) / EPB), dim3(512), 0, stream>>>(Xa, Eidx, Wt, edge_b, edge_g, edge_lb, outE, N);
}

// Round 5
// 168.072 us; speedup vs baseline: 1.6338x; 1.6338x over previous
//
#include <hip/hip_runtime.h>
#include <hip/hip_bf16.h>

#define TOPK 30
#define NAT 14
#define EDGE_IN 3152   // 16 PE + 14*14*16 RBF
#define KPAD 3168      // padded to 99 chunks of 32
#define NCHUNK 99
#define EPB 64         // edges per k_edge block

typedef __attribute__((ext_vector_type(8))) short bf16x8;
typedef __attribute__((ext_vector_type(4))) float f32x4;

typedef const __attribute__((address_space(1))) void* gptr_t;
typedef __attribute__((address_space(3))) void* lptr_t;

__device__ __forceinline__ unsigned short f2bf(float f) {
    union { float f; unsigned u; } v; v.f = f;
    unsigned r = v.u + 0x7FFF + ((v.u >> 16) & 1);   // RNE
    return (unsigned short)(r >> 16);
}
__device__ __forceinline__ float bf2f(unsigned short h) {
    union { unsigned u; float f; } v; v.u = ((unsigned)h) << 16;
    return v.f;
}

// ---------------- Xa = [N, Ca, C, O, Cb, sc9] ----------------
__global__ void k_prep(const float* __restrict__ X, float* __restrict__ Xa, int N) {
    int i = blockIdx.x * blockDim.x + threadIdx.x;
    if (i >= N) return;
    const float* xi = X + (size_t)i * NAT * 3;
    float* xo = Xa + (size_t)i * NAT * 3;
    float Nx = xi[0], Ny = xi[1], Nz = xi[2];
    float Ax = xi[3], Ay = xi[4], Az = xi[5];
    float Cx = xi[6], Cy = xi[7], Cz = xi[8];
    float bx = Ax - Nx, by = Ay - Ny, bz = Az - Nz;
    float cx = Cx - Ax, cy = Cy - Ay, cz = Cz - Az;
    float ax = by * cz - bz * cy;
    float ay = bz * cx - bx * cz;
    float az = bx * cy - by * cx;
    float Cbx = -0.58273431f * ax + 0.56802827f * bx - 0.54067466f * cx + Ax;
    float Cby = -0.58273431f * ay + 0.56802827f * by - 0.54067466f * cy + Ay;
    float Cbz = -0.58273431f * az + 0.56802827f * bz - 0.54067466f * cz + Az;
#pragma unroll
    for (int a = 0; a < 4; a++) { xo[a*3] = xi[a*3]; xo[a*3+1] = xi[a*3+1]; xo[a*3+2] = xi[a*3+2]; }
    xo[12] = Cbx; xo[13] = Cby; xo[14] = Cbz;
#pragma unroll
    for (int a = 5; a < 14; a++) { xo[a*3] = xi[a*3]; xo[a*3+1] = xi[a*3+1]; xo[a*3+2] = xi[a*3+2]; }
}

// ---------------- Wt[c][k] = bf16(edge_w[k][c]), zero-padded to KPAD ----------------
__global__ void k_wt(const float* __restrict__ W, unsigned short* __restrict__ Wt) {
    __shared__ unsigned short tile[32][33];
    int kb = blockIdx.x * 32, cb = blockIdx.y * 32;
    int tx = threadIdx.x, ty = threadIdx.y;   // (32,8)
#pragma unroll
    for (int r = 0; r < 32; r += 8) {
        int k = kb + ty + r;
        float v = (k < EDGE_IN) ? W[(size_t)k * 128 + cb + tx] : 0.f;
        tile[ty + r][tx] = f2bf(v);
    }
    __syncthreads();
#pragma unroll
    for (int r = 0; r < 32; r += 8)
        Wt[(size_t)(cb + ty + r) * KPAD + kb + tx] = tile[tx][ty + r];
}

// ---------------- exact stable KNN in FLOAT64 (one block per residue) ----------------
__global__ __launch_bounds__(256) void k_knn(const float* __restrict__ X, const float* __restrict__ mask,
                                             int* __restrict__ Eidx, float* __restrict__ outI, int N) {
    __shared__ double sD[1024];
    __shared__ double sMax[4];
    __shared__ double sBd[4];
    __shared__ int    sBi[4];
    int i = blockIdx.x, t = threadIdx.x;
    double mi = (double)mask[i];
    double xx = (double)X[((size_t)i * NAT + 1) * 3 + 0];
    double xy = (double)X[((size_t)i * NAT + 1) * 3 + 1];
    double xz = (double)X[((size_t)i * NAT + 1) * 3 + 2];
    double lmax = -1.0;
    for (int j = t; j < N; j += 256) {
        double dx = xx - (double)X[((size_t)j * NAT + 1) * 3 + 0];
        double dy = xy - (double)X[((size_t)j * NAT + 1) * 3 + 1];
        double dz = xz - (double)X[((size_t)j * NAT + 1) * 3 + 2];
        double s = ((dx * dx + dy * dy) + dz * dz) + 1e-6;
        double d = (mi * (double)mask[j]) * sqrt(s);
        sD[j] = d;
        lmax = fmax(lmax, d);
    }
#pragma unroll
    for (int m = 32; m; m >>= 1) lmax = fmax(lmax, __shfl_xor(lmax, m));
    if ((t & 63) == 0) sMax[t >> 6] = lmax;
    __syncthreads();
    double Dmax = fmax(fmax(sMax[0], sMax[1]), fmax(sMax[2], sMax[3]));
    for (int j = t; j < N; j += 256) {
        double m2 = mi * (double)mask[j];
        sD[j] = sD[j] + 2.0 * (1.0 - m2) * Dmax;
    }
    __syncthreads();
    for (int s = 0; s < TOPK; s++) {
        double bd = 1e300;
        int bi = 0x7FFFFFFF;
        for (int j = t; j < N; j += 256) {
            double d = sD[j];
            if (d < bd || (d == bd && j < bi)) { bd = d; bi = j; }
        }
#pragma unroll
        for (int m = 32; m; m >>= 1) {
            double od = __shfl_xor(bd, m);
            int oi = __shfl_xor(bi, m);
            if (od < bd || (od == bd && oi < bi)) { bd = od; bi = oi; }
        }
        if ((t & 63) == 0) { sBd[t >> 6] = bd; sBi[t >> 6] = bi; }
        __syncthreads();
        if (t == 0) {
            double d0 = sBd[0]; int i0 = sBi[0];
#pragma unroll
            for (int w = 1; w < 4; w++) {
                if (sBd[w] < d0 || (sBd[w] == d0 && sBi[w] < i0)) { d0 = sBd[w]; i0 = sBi[w]; }
            }
            Eidx[(size_t)i * TOPK + s] = i0;
            outI[(size_t)i * TOPK + s] = (float)i0;
            sD[i0] = 1e300;
        }
        __syncthreads();
    }
}

// ---------------- node: onehot-gather + matvec + LN (one wave per residue) ----------------
__global__ __launch_bounds__(64) void k_node(const int* __restrict__ S, const float* __restrict__ BB,
                                             const float* __restrict__ W, const float* __restrict__ nb,
                                             const float* __restrict__ g, const float* __restrict__ be,
                                             float* __restrict__ outV, int N) {
    int i = blockIdx.x, t = threadIdx.x;
    int s = S[i];
    float b0 = BB[i*6], b1 = BB[i*6+1], b2 = BB[i*6+2], b3 = BB[i*6+3], b4 = BB[i*6+4], b5 = BB[i*6+5];
    int t2 = t + 64;
    float x0 = W[(size_t)s*128 + t] + nb[t]
             + b0*W[21*128+t] + b1*W[22*128+t] + b2*W[23*128+t]
             + b3*W[24*128+t] + b4*W[25*128+t] + b5*W[26*128+t];
    float x1 = W[(size_t)s*128 + t2] + nb[t2]
             + b0*W[21*128+t2] + b1*W[22*128+t2] + b2*W[23*128+t2]
             + b3*W[24*128+t2] + b4*W[25*128+t2] + b5*W[26*128+t2];
    float sum = x0 + x1;
#pragma unroll
    for (int m = 32; m; m >>= 1) sum += __shfl_xor(sum, m);
    float mean = sum * (1.f / 128.f);
    float d0 = x0 - mean, d1 = x1 - mean;
    float vs = d0*d0 + d1*d1;
#pragma unroll
    for (int m = 32; m; m >>= 1) vs += __shfl_xor(vs, m);
    float inv = 1.f / sqrtf(vs * (1.f / 128.f) + 1e-5f);
    outV[(size_t)i*128 + t]  = d0 * inv * g[t]  + be[t];
    outV[(size_t)i*128 + t2] = d1 * inv * g[t2] + be[t2];
}

// ---------------- fused edge features + bf16 MFMA GEMM + LN ----------------
// 64 edges/block, 4 waves, full K per wave. B K-chunks staged in LDS
// (double-buffered global_load_lds, counted vmcnt) and shared by all waves.
// B LDS layout [koff][col][8k] -> ds_read_b128 2-way conflict (free).
__global__ __launch_bounds__(256) void k_edge(const float* __restrict__ Xa, const int* __restrict__ Eidx,
                                              const unsigned short* __restrict__ Wt,
                                              const float* __restrict__ ebias, const float* __restrict__ egain,
                                              const float* __restrict__ ebeta,
                                              float* __restrict__ outE, int N) {
    __shared__ unsigned short sDh[EPB * 200];            // bf16 D, stride 200: 16 lanes -> 16 banks
    __shared__ float sDpe[EPB];
    __shared__ __align__(16) unsigned short sB[2][4096]; // 2 x 8KB B chunk buffers
    const int NE = N * TOPK;
    int t = threadIdx.x;
    int geBase = blockIdx.x * EPB;
    {
        int le = t >> 2, q = t & 3;       // 4 threads per edge
        int ge = geBase + le; if (ge >= NE) ge = NE - 1;
        int i = ge / TOPK;
        int j = Eidx[ge];
        if (q == 0) sDpe[le] = (float)j - (float)i;
        const float* Xi = Xa + (size_t)i * NAT * 3;
        const float* Xj = Xa + (size_t)j * NAT * 3;
        for (int p = q; p < 196; p += 4) {
            int a = p / 14, b = p - 14 * a;
            float dx = Xi[a*3+0] - Xj[b*3+0];
            float dy = Xi[a*3+1] - Xj[b*3+1];
            float dz = Xi[a*3+2] - Xj[b*3+2];
            sDh[le * 200 + p] = f2bf(sqrtf(dx*dx + dy*dy + dz*dz + 1e-6f));
        }
    }

    int ln = t & 63, wid = t >> 6;
    int lrow = ln & 15, koff = ln >> 4;
    int leA = wid * 16 + lrow;            // this lane's A-row (edge)
    const unsigned short* sDrow = sDh + leA * 200;

    // staging: thread t loads Wt[col=t&127][kc*32 + (t>>7)*8] (issue 0) and
    // Wt[col][kc*32 + (2+(t>>7))*8] (issue 1); LDS fills linearly lane*16.
    const unsigned short* gB0 = Wt + (size_t)(t & 127) * KPAD + (t >> 7) * 8;
    const unsigned short* gB1 = gB0 + 16;
    unsigned short* lB0a = &sB[0][(size_t)wid * 512];          // bytes wid*1024 (wave-uniform)
    unsigned short* lB1a = &sB[0][2048 + (size_t)wid * 512];   // + 4096 bytes
    unsigned short* lB0b = &sB[1][(size_t)wid * 512];
    unsigned short* lB1b = &sB[1][2048 + (size_t)wid * 512];

    // prologue: stage chunk 0 into buffer 0
    __builtin_amdgcn_global_load_lds((gptr_t)(const void*)gB0, (lptr_t)(void*)lB0a, 16, 0, 0);
    __builtin_amdgcn_global_load_lds((gptr_t)(const void*)gB1, (lptr_t)(void*)lB1a, 16, 0, 0);

    f32x4 acc[8];
#pragma unroll
    for (int f = 0; f < 8; f++) acc[f] = (f32x4){0.f, 0.f, 0.f, 0.f};
    float dpe = 0.f;

    for (int kc = 0; kc < NCHUNK; kc++) {
        int cur = kc & 1;
        if (kc + 1 < NCHUNK) {            // stage next chunk into the other buffer
            const unsigned short* g0 = gB0 + (size_t)(kc + 1) * 32;
            const unsigned short* g1 = gB1 + (size_t)(kc + 1) * 32;
            __builtin_amdgcn_global_load_lds((gptr_t)(const void*)g0, (lptr_t)(void*)(cur ? lB0a : lB0b), 16, 0, 0);
            __builtin_amdgcn_global_load_lds((gptr_t)(const void*)g1, (lptr_t)(void*)(cur ? lB1a : lB1b), 16, 0, 0);
            asm volatile("s_waitcnt vmcnt(2)" ::: "memory");   // drain stage(kc); keep stage(kc+1) flying
        } else {
            asm volatile("s_waitcnt vmcnt(0)" ::: "memory");
        }
        __syncthreads();                   // all waves' stage(kc) visible (and phase-1 D on kc==0)

        if (kc == 0) dpe = sDpe[leA];

        int kb = kc * 32 + koff * 8;
        bf16x8 afrag;
        if (kb < 16) {
#pragma unroll
            for (int jj = 0; jj < 8; jj++) {
                float fr = __expf(-1.1512925f * (float)jj);   // 10000^(-2m/16)
                float ang = dpe * fr;
                float v = (kb == 0) ? cosf(ang) : sinf(ang);
                afrag[jj] = (short)f2bf(v);
            }
        } else if (kb >= EDGE_IN) {
#pragma unroll
            for (int jj = 0; jj < 8; jj++) afrag[jj] = 0;
        } else {
            int pk = kb - 16;              // 8 consecutive k never cross a pair
            float D = bf2f(sDrow[pk >> 4]);
            float base = (float)(pk & 15);
#pragma unroll
            for (int jj = 0; jj < 8; jj++) {
                float mu = (base + (float)jj) * 1.3333334f;   // linspace(0,20,16)
                float tt = (D - mu) * 0.8f;                   // /1.25
                afrag[jj] = (short)f2bf(__expf(-tt * tt));
            }
        }
        const unsigned short* bbuf = sB[cur];
#pragma unroll
        for (int f = 0; f < 8; f++) {
            bf16x8 bfrag = *reinterpret_cast<const bf16x8*>(bbuf + ((size_t)koff * 128 + f * 16 + lrow) * 8);
            acc[f] = __builtin_amdgcn_mfma_f32_16x16x32_bf16(afrag, bfrag, acc[f], 0, 0, 0);
        }
        __syncthreads();                   // all reads of buf[cur] done before restage next iter
    }

    // epilogue: +bias, LN over 128 cols (reduce across 16-lane group), f32 store
    float gg[8], bb2[8], eb[8];
#pragma unroll
    for (int f = 0; f < 8; f++) { int c = f * 16 + lrow; gg[f] = egain[c]; bb2[f] = ebeta[c]; eb[f] = ebias[c]; }
#pragma unroll
    for (int r = 0; r < 4; r++) {
        float x[8], sum = 0.f;
#pragma unroll
        for (int f = 0; f < 8; f++) { x[f] = acc[f][r] + eb[f]; sum += x[f]; }
#pragma unroll
        for (int m = 1; m < 16; m <<= 1) sum += __shfl_xor(sum, m);
        float mean = sum * (1.f / 128.f);
        float vs = 0.f;
#pragma unroll
        for (int f = 0; f < 8; f++) { float d2 = x[f] - mean; vs += d2 * d2; }
#pragma unroll
        for (int m = 1; m < 16; m <<= 1) vs += __shfl_xor(vs, m);
        float inv = 1.f / sqrtf(vs * (1.f / 128.f) + 1e-5f);
        int row = geBase + wid * 16 + koff * 4 + r;
        if (row < NE) {
            float* po = outE + (size_t)row * 128 + lrow;
#pragma unroll
            for (int f = 0; f < 8; f++) po[f * 16] = (x[f] - mean) * inv * gg[f] + bb2[f];
        }
    }
}

extern "C" void kernel_launch(void* const* d_in, const int* in_sizes, int n_in,
                              void* d_out, int out_size, void* d_ws, size_t ws_size,
                              hipStream_t stream) {
    const float* X       = (const float*)d_in[0];
    const int*   S       = (const int*)d_in[1];
    const float* BB      = (const float*)d_in[2];
    const float* mask    = (const float*)d_in[3];
    const float* node_w  = (const float*)d_in[4];
    const float* node_b  = (const float*)d_in[5];
    const float* node_g  = (const float*)d_in[6];
    const float* node_lb = (const float*)d_in[7];
    const float* edge_w  = (const float*)d_in[8];
    const float* edge_b  = (const float*)d_in[9];
    const float* edge_g  = (const float*)d_in[10];
    const float* edge_lb = (const float*)d_in[11];
    int N  = in_sizes[1];       // 1024
    int NE = N * TOPK;

    float* out  = (float*)d_out;
    float* outV = out;                                  // N*128 f32
    float* outE = out + (size_t)N * 128;                // NE*128 f32
    float* outI = outE + (size_t)NE * 128;              // NE f32

    char* ws = (char*)d_ws;
    int* Eidx = (int*)ws;
    size_t off = ((size_t)NE * 4 + 255) & ~(size_t)255;
    float* Xa = (float*)(ws + off);
    off += (((size_t)N * NAT * 3 * 4) + 255) & ~(size_t)255;
    unsigned short* Wt = (unsigned short*)(ws + off);   // 128*KPAD bf16

    k_prep<<<dim3((N + 255) / 256), dim3(256), 0, stream>>>(X, Xa, N);
    k_wt<<<dim3(KPAD / 32, 128 / 32), dim3(32, 8), 0, stream>>>(edge_w, Wt);
    k_knn<<<dim3(N), dim3(256), 0, stream>>>(X, mask, Eidx, outI, N);
    k_node<<<dim3(N), dim3(64), 0, stream>>>(S, BB, node_w, node_b, node_g, node_lb, outV, N);
    k_edge<<<dim3((NE + EPB - 1) / EPB), dim3(256), 0, stream>>>(Xa, Eidx, Wt, edge_b, edge_g, edge_lb, outE, N);
}

// Round 6
// 147.552 us; speedup vs baseline: 1.8610x; 1.1391x over previous
//
#include <hip/hip_runtime.h>
#include <hip/hip_bf16.h>

#define TOPK 30
#define NAT 14
#define EDGE_IN 3152   // 16 PE + 14*14*16 RBF
#define KPAD 3168      // padded to 99 chunks of 32
#define NCHUNK 99
#define EPB 64         // edges per k_edge block

typedef __attribute__((ext_vector_type(8))) short bf16x8;
typedef __attribute__((ext_vector_type(4))) float f32x4;

typedef const __attribute__((address_space(1))) void* gptr_t;
typedef __attribute__((address_space(3))) void* lptr_t;

__device__ __forceinline__ unsigned short f2bf(float f) {
    union { float f; unsigned u; } v; v.f = f;
    unsigned r = v.u + 0x7FFF + ((v.u >> 16) & 1);   // RNE
    return (unsigned short)(r >> 16);
}
__device__ __forceinline__ float bf2f(unsigned short h) {
    union { unsigned u; float f; } v; v.u = ((unsigned)h) << 16;
    return v.f;
}

// ---------------- Xa = [N, Ca, C, O, Cb, sc9] ----------------
__global__ void k_prep(const float* __restrict__ X, float* __restrict__ Xa, int N) {
    int i = blockIdx.x * blockDim.x + threadIdx.x;
    if (i >= N) return;
    const float* xi = X + (size_t)i * NAT * 3;
    float* xo = Xa + (size_t)i * NAT * 3;
    float Nx = xi[0], Ny = xi[1], Nz = xi[2];
    float Ax = xi[3], Ay = xi[4], Az = xi[5];
    float Cx = xi[6], Cy = xi[7], Cz = xi[8];
    float bx = Ax - Nx, by = Ay - Ny, bz = Az - Nz;
    float cx = Cx - Ax, cy = Cy - Ay, cz = Cz - Az;
    float ax = by * cz - bz * cy;
    float ay = bz * cx - bx * cz;
    float az = bx * cy - by * cx;
    float Cbx = -0.58273431f * ax + 0.56802827f * bx - 0.54067466f * cx + Ax;
    float Cby = -0.58273431f * ay + 0.56802827f * by - 0.54067466f * cy + Ay;
    float Cbz = -0.58273431f * az + 0.56802827f * bz - 0.54067466f * cz + Az;
#pragma unroll
    for (int a = 0; a < 4; a++) { xo[a*3] = xi[a*3]; xo[a*3+1] = xi[a*3+1]; xo[a*3+2] = xi[a*3+2]; }
    xo[12] = Cbx; xo[13] = Cby; xo[14] = Cbz;
#pragma unroll
    for (int a = 5; a < 14; a++) { xo[a*3] = xi[a*3]; xo[a*3+1] = xi[a*3+1]; xo[a*3+2] = xi[a*3+2]; }
}

// ---------------- Wt[c][k] = bf16(edge_w[k][c]), zero-padded to KPAD ----------------
__global__ void k_wt(const float* __restrict__ W, unsigned short* __restrict__ Wt) {
    __shared__ unsigned short tile[32][33];
    int kb = blockIdx.x * 32, cb = blockIdx.y * 32;
    int tx = threadIdx.x, ty = threadIdx.y;   // (32,8)
#pragma unroll
    for (int r = 0; r < 32; r += 8) {
        int k = kb + ty + r;
        float v = (k < EDGE_IN) ? W[(size_t)k * 128 + cb + tx] : 0.f;
        tile[ty + r][tx] = f2bf(v);
    }
    __syncthreads();
#pragma unroll
    for (int r = 0; r < 32; r += 8)
        Wt[(size_t)(cb + ty + r) * KPAD + kb + tx] = tile[tx][ty + r];
}

// ---------------- exact stable KNN in FLOAT64 (one block per residue) ----------------
__global__ __launch_bounds__(256) void k_knn(const float* __restrict__ X, const float* __restrict__ mask,
                                             int* __restrict__ Eidx, float* __restrict__ outI, int N) {
    __shared__ double sD[1024];
    __shared__ double sMax[4];
    __shared__ double sBd[4];
    __shared__ int    sBi[4];
    int i = blockIdx.x, t = threadIdx.x;
    double mi = (double)mask[i];
    double xx = (double)X[((size_t)i * NAT + 1) * 3 + 0];
    double xy = (double)X[((size_t)i * NAT + 1) * 3 + 1];
    double xz = (double)X[((size_t)i * NAT + 1) * 3 + 2];
    double lmax = -1.0;
    for (int j = t; j < N; j += 256) {
        double dx = xx - (double)X[((size_t)j * NAT + 1) * 3 + 0];
        double dy = xy - (double)X[((size_t)j * NAT + 1) * 3 + 1];
        double dz = xz - (double)X[((size_t)j * NAT + 1) * 3 + 2];
        double s = ((dx * dx + dy * dy) + dz * dz) + 1e-6;
        double d = (mi * (double)mask[j]) * sqrt(s);
        sD[j] = d;
        lmax = fmax(lmax, d);
    }
#pragma unroll
    for (int m = 32; m; m >>= 1) lmax = fmax(lmax, __shfl_xor(lmax, m));
    if ((t & 63) == 0) sMax[t >> 6] = lmax;
    __syncthreads();
    double Dmax = fmax(fmax(sMax[0], sMax[1]), fmax(sMax[2], sMax[3]));
    for (int j = t; j < N; j += 256) {
        double m2 = mi * (double)mask[j];
        sD[j] = sD[j] + 2.0 * (1.0 - m2) * Dmax;
    }
    __syncthreads();
    for (int s = 0; s < TOPK; s++) {
        double bd = 1e300;
        int bi = 0x7FFFFFFF;
        for (int j = t; j < N; j += 256) {
            double d = sD[j];
            if (d < bd || (d == bd && j < bi)) { bd = d; bi = j; }
        }
#pragma unroll
        for (int m = 32; m; m >>= 1) {
            double od = __shfl_xor(bd, m);
            int oi = __shfl_xor(bi, m);
            if (od < bd || (od == bd && oi < bi)) { bd = od; bi = oi; }
        }
        if ((t & 63) == 0) { sBd[t >> 6] = bd; sBi[t >> 6] = bi; }
        __syncthreads();
        if (t == 0) {
            double d0 = sBd[0]; int i0 = sBi[0];
#pragma unroll
            for (int w = 1; w < 4; w++) {
                if (sBd[w] < d0 || (sBd[w] == d0 && sBi[w] < i0)) { d0 = sBd[w]; i0 = sBi[w]; }
            }
            Eidx[(size_t)i * TOPK + s] = i0;
            outI[(size_t)i * TOPK + s] = (float)i0;
            sD[i0] = 1e300;
        }
        __syncthreads();
    }
}

// ---------------- node: onehot-gather + matvec + LN (one wave per residue) ----------------
__global__ __launch_bounds__(64) void k_node(const int* __restrict__ S, const float* __restrict__ BB,
                                             const float* __restrict__ W, const float* __restrict__ nb,
                                             const float* __restrict__ g, const float* __restrict__ be,
                                             float* __restrict__ outV, int N) {
    int i = blockIdx.x, t = threadIdx.x;
    int s = S[i];
    float b0 = BB[i*6], b1 = BB[i*6+1], b2 = BB[i*6+2], b3 = BB[i*6+3], b4 = BB[i*6+4], b5 = BB[i*6+5];
    int t2 = t + 64;
    float x0 = W[(size_t)s*128 + t] + nb[t]
             + b0*W[21*128+t] + b1*W[22*128+t] + b2*W[23*128+t]
             + b3*W[24*128+t] + b4*W[25*128+t] + b5*W[26*128+t];
    float x1 = W[(size_t)s*128 + t2] + nb[t2]
             + b0*W[21*128+t2] + b1*W[22*128+t2] + b2*W[23*128+t2]
             + b3*W[24*128+t2] + b4*W[25*128+t2] + b5*W[26*128+t2];
    float sum = x0 + x1;
#pragma unroll
    for (int m = 32; m; m >>= 1) sum += __shfl_xor(sum, m);
    float mean = sum * (1.f / 128.f);
    float d0 = x0 - mean, d1 = x1 - mean;
    float vs = d0*d0 + d1*d1;
#pragma unroll
    for (int m = 32; m; m >>= 1) vs += __shfl_xor(vs, m);
    float inv = 1.f / sqrtf(vs * (1.f / 128.f) + 1e-5f);
    outV[(size_t)i*128 + t]  = d0 * inv * g[t]  + be[t];
    outV[(size_t)i*128 + t2] = d1 * inv * g[t2] + be[t2];
}

// ---------------- fused edge features + bf16 MFMA GEMM + LN ----------------
// 64 edges/block, 4 waves, full K per wave. B K-chunks TRIPLE-buffered in LDS
// via global_load_lds; ONE raw s_barrier per chunk; counted vmcnt(2) keeps the
// next stage in flight ACROSS the barrier (never __syncthreads in the loop —
// it drains vmcnt to 0 and defeats the pipeline).
__global__ __launch_bounds__(256) void k_edge(const float* __restrict__ Xa, const int* __restrict__ Eidx,
                                              const unsigned short* __restrict__ Wt,
                                              const float* __restrict__ ebias, const float* __restrict__ egain,
                                              const float* __restrict__ ebeta,
                                              float* __restrict__ outE, int N) {
    __shared__ unsigned short sDh[EPB * 200];            // bf16 D, stride 200
    __shared__ float sDpe[EPB];
    __shared__ __align__(16) unsigned short sB[3][4096]; // 3 x 8KB B chunk buffers
    const int NE = N * TOPK;
    int t = threadIdx.x;
    int geBase = blockIdx.x * EPB;
    int ln = t & 63, wid = t >> 6;

    // staging addresses: thread t covers Wt[col=t&127][kc*32 + (t>>7)*8] (issue 0)
    // and Wt[col][kc*32 + (2+(t>>7))*8] (issue 1); LDS fills linearly lane*16B.
    const unsigned short* gB0 = Wt + (size_t)(t & 127) * KPAD + (t >> 7) * 8;
    const unsigned short* gB1 = gB0 + 16;

    // prologue: stage chunks 0,1 immediately so they fly under the D-table build
    {
        unsigned short* l0 = &sB[0][(size_t)wid * 512];
        unsigned short* l1 = &sB[0][2048 + (size_t)wid * 512];
        __builtin_amdgcn_global_load_lds((gptr_t)(const void*)gB0, (lptr_t)(void*)l0, 16, 0, 0);
        __builtin_amdgcn_global_load_lds((gptr_t)(const void*)gB1, (lptr_t)(void*)l1, 16, 0, 0);
        unsigned short* m0 = &sB[1][(size_t)wid * 512];
        unsigned short* m1 = &sB[1][2048 + (size_t)wid * 512];
        __builtin_amdgcn_global_load_lds((gptr_t)(const void*)(gB0 + 32), (lptr_t)(void*)m0, 16, 0, 0);
        __builtin_amdgcn_global_load_lds((gptr_t)(const void*)(gB1 + 32), (lptr_t)(void*)m1, 16, 0, 0);
    }

    // D-table build: 4 threads per edge
    {
        int le = t >> 2, q = t & 3;
        int ge = geBase + le; if (ge >= NE) ge = NE - 1;
        int i = ge / TOPK;
        int j = Eidx[ge];
        if (q == 0) sDpe[le] = (float)j - (float)i;
        const float* Xi = Xa + (size_t)i * NAT * 3;
        const float* Xj = Xa + (size_t)j * NAT * 3;
        for (int p = q; p < 196; p += 4) {
            int a = p / 14, b = p - 14 * a;
            float dx = Xi[a*3+0] - Xj[b*3+0];
            float dy = Xi[a*3+1] - Xj[b*3+1];
            float dz = Xi[a*3+2] - Xj[b*3+2];
            sDh[le * 200 + p] = f2bf(sqrtf(dx*dx + dy*dy + dz*dz + 1e-6f));
        }
    }
    asm volatile("s_waitcnt lgkmcnt(0)" ::: "memory");   // our D/PE ds_writes done

    int lrow = ln & 15, koff = ln >> 4;
    int leA = wid * 16 + lrow;            // this lane's A-row (edge)
    const unsigned short* sDrow = sDh + leA * 200;

    f32x4 acc[8];
#pragma unroll
    for (int f = 0; f < 8; f++) acc[f] = (f32x4){0.f, 0.f, 0.f, 0.f};
    float dpe = 0.f;

    for (int kc = 0; kc < NCHUNK; kc++) {
        // wait: stage(kc) landed; stage(kc+1)'s 2 issues may stay in flight
        if (kc < NCHUNK - 1) { asm volatile("s_waitcnt vmcnt(2)" ::: "memory"); }
        else                 { asm volatile("s_waitcnt vmcnt(0)" ::: "memory"); }
        __builtin_amdgcn_s_barrier();     // raw: does NOT drain vmcnt
        __builtin_amdgcn_sched_barrier(0);

        // stage chunk kc+2 into buf[(kc+2)%3] — last read at chunk kc-1, sealed above
        if (kc + 2 < NCHUNK) {
            int b = (kc + 2) % 3;
            unsigned short* l0 = &sB[b][(size_t)wid * 512];
            unsigned short* l1 = &sB[b][2048 + (size_t)wid * 512];
            const unsigned short* g0 = gB0 + (size_t)(kc + 2) * 32;
            const unsigned short* g1 = gB1 + (size_t)(kc + 2) * 32;
            __builtin_amdgcn_global_load_lds((gptr_t)(const void*)g0, (lptr_t)(void*)l0, 16, 0, 0);
            __builtin_amdgcn_global_load_lds((gptr_t)(const void*)g1, (lptr_t)(void*)l1, 16, 0, 0);
        }

        if (kc == 0) dpe = sDpe[leA];

        int kb = kc * 32 + koff * 8;
        bf16x8 afrag;
        if (kb < 16) {
#pragma unroll
            for (int jj = 0; jj < 8; jj++) {
                float fr = __expf(-1.1512925f * (float)jj);   // 10000^(-2m/16)
                float ang = dpe * fr;
                float v = (kb == 0) ? cosf(ang) : sinf(ang);
                afrag[jj] = (short)f2bf(v);
            }
        } else if (kb >= EDGE_IN) {
#pragma unroll
            for (int jj = 0; jj < 8; jj++) afrag[jj] = 0;
        } else {
            int pk = kb - 16;              // 8 consecutive k never cross a pair
            float D = bf2f(sDrow[pk >> 4]);
            float base = (float)(pk & 15);
#pragma unroll
            for (int jj = 0; jj < 8; jj++) {
                float mu = (base + (float)jj) * 1.3333334f;   // linspace(0,20,16)
                float tt = (D - mu) * 0.8f;                   // /1.25
                afrag[jj] = (short)f2bf(__expf(-tt * tt));
            }
        }
        const unsigned short* bbuf = sB[kc % 3];
#pragma unroll
        for (int f = 0; f < 8; f++) {
            bf16x8 bfrag = *reinterpret_cast<const bf16x8*>(bbuf + ((size_t)koff * 128 + f * 16 + lrow) * 8);
            acc[f] = __builtin_amdgcn_mfma_f32_16x16x32_bf16(afrag, bfrag, acc[f], 0, 0, 0);
        }
        // no trailing barrier: next iter's barrier seals reads of this buffer
    }

    // epilogue: +bias, LN over 128 cols (reduce across 16-lane group), f32 store
    float gg[8], bb2[8], eb[8];
#pragma unroll
    for (int f = 0; f < 8; f++) { int c = f * 16 + lrow; gg[f] = egain[c]; bb2[f] = ebeta[c]; eb[f] = ebias[c]; }
#pragma unroll
    for (int r = 0; r < 4; r++) {
        float x[8], sum = 0.f;
#pragma unroll
        for (int f = 0; f < 8; f++) { x[f] = acc[f][r] + eb[f]; sum += x[f]; }
#pragma unroll
        for (int m = 1; m < 16; m <<= 1) sum += __shfl_xor(sum, m);
        float mean = sum * (1.f / 128.f);
        float vs = 0.f;
#pragma unroll
        for (int f = 0; f < 8; f++) { float d2 = x[f] - mean; vs += d2 * d2; }
#pragma unroll
        for (int m = 1; m < 16; m <<= 1) vs += __shfl_xor(vs, m);
        float inv = 1.f / sqrtf(vs * (1.f / 128.f) + 1e-5f);
        int row = geBase + wid * 16 + koff * 4 + r;
        if (row < NE) {
            float* po = outE + (size_t)row * 128 + lrow;
#pragma unroll
            for (int f = 0; f < 8; f++) po[f * 16] = (x[f] - mean) * inv * gg[f] + bb2[f];
        }
    }
}

extern "C" void kernel_launch(void* const* d_in, const int* in_sizes, int n_in,
                              void* d_out, int out_size, void* d_ws, size_t ws_size,
                              hipStream_t stream) {
    const float* X       = (const float*)d_in[0];
    const int*   S       = (const int*)d_in[1];
    const float* BB      = (const float*)d_in[2];
    const float* mask    = (const float*)d_in[3];
    const float* node_w  = (const float*)d_in[4];
    const float* node_b  = (const float*)d_in[5];
    const float* node_g  = (const float*)d_in[6];
    const float* node_lb = (const float*)d_in[7];
    const float* edge_w  = (const float*)d_in[8];
    const float* edge_b  = (const float*)d_in[9];
    const float* edge_g  = (const float*)d_in[10];
    const float* edge_lb = (const float*)d_in[11];
    int N  = in_sizes[1];       // 1024
    int NE = N * TOPK;

    float* out  = (float*)d_out;
    float* outV = out;                                  // N*128 f32
    float* outE = out + (size_t)N * 128;                // NE*128 f32
    float* outI = outE + (size_t)NE * 128;              // NE f32

    char* ws = (char*)d_ws;
    int* Eidx = (int*)ws;
    size_t off = ((size_t)NE * 4 + 255) & ~(size_t)255;
    float* Xa = (float*)(ws + off);
    off += (((size_t)N * NAT * 3 * 4) + 255) & ~(size_t)255;
    unsigned short* Wt = (unsigned short*)(ws + off);   // 128*KPAD bf16

    k_prep<<<dim3((N + 255) / 256), dim3(256), 0, stream>>>(X, Xa, N);
    k_wt<<<dim3(KPAD / 32, 128 / 32), dim3(32, 8), 0, stream>>>(edge_w, Wt);
    k_knn<<<dim3(N), dim3(256), 0, stream>>>(X, mask, Eidx, outI, N);
    k_node<<<dim3(N), dim3(64), 0, stream>>>(S, BB, node_w, node_b, node_g, node_lb, outV, N);
    k_edge<<<dim3((NE + EPB - 1) / EPB), dim3(256), 0, stream>>>(Xa, Eidx, Wt, edge_b, edge_g, edge_lb, outE, N);
}